// Round 2
// baseline (674.973 us; speedup 1.0000x reference)
//
#include <hip/hip_runtime.h>
#include <hip/hip_bf16.h>

// RoutingCapsule: x(B,I,P) fp32, W(1,I,O,D,P) fp32, bias(1,1,O,D,1) fp32 -> v(B,O,D) fp32
// B=16 I=2048 P=16 O=64 D=32.  Routing collapses (b_logits additive, starts at 0):
//   s0 = (1/64) sum_i u ; v0 = squash(s0+bias)
//   pass1: c1 = softmax_o(u.v0)      ; s1 = sum_i c1*u ; v1 = squash(s1+bias)
//   pass2: c2 = softmax_o(u.(v0+v1)) ; s2 = sum_i c2*u ; out = squash(s2+bias)
// u_hat MUST be fp32: bf16's 4e-3/elem error is amplified ~30x by the iterated
// softmax routing (spiky c, sum_i c^2 ~ 32) -> observed 0.465 absmax in R1.
#define B_ 16
#define I_ 2048
#define P_ 16
#define O_ 64
#define D_ 32
#define OD_ 2048
#define EPSQ 1e-9f

__device__ __forceinline__ float squashf(float s) {
  float sq = s * s;
  return sq / (1.0f + sq) * s * rsqrtf(sq + EPSQ);
}

// ---------------------------------------------------------------------------
// K1: u[b,i,od] = sum_p x[b,i,p]*W[i,od,p], fp32.
// grid=1024: bx&3 = od-quarter, bx>>2 = i-chunk of 8. Thread owns od-pair pr:
// 2 W rows = 128 B/lane (coalesced 8KB/wave); x loads wave-uniform (cached).
// ---------------------------------------------------------------------------
__global__ __launch_bounds__(256) void k_uhat(
    const float* __restrict__ x, const float* __restrict__ W,
    float* __restrict__ u)
{
  const int t = threadIdx.x;
  const int q = blockIdx.x & 3;
  const int i0 = (blockIdx.x >> 2) * 8;
  const int pr = q * 256 + t;  // od-pair 0..1023

  for (int ii = 0; ii < 8; ++ii) {
    const int i = i0 + ii;
    const float4* wp = (const float4*)(W + (size_t)(i * OD_ + pr * 2) * P_);
    float4 w[8];
#pragma unroll
    for (int k = 0; k < 8; ++k) w[k] = wp[k];

#pragma unroll
    for (int b = 0; b < B_; ++b) {
      const float4* xp = (const float4*)(x + (size_t)(b * I_ + i) * P_);
      float u0 = 0.f, u1 = 0.f;
#pragma unroll
      for (int qq = 0; qq < 4; ++qq) {
        float4 xq = xp[qq];
        float4 wa = w[qq], wb = w[qq + 4];
        u0 += xq.x * wa.x + xq.y * wa.y + xq.z * wa.z + xq.w * wa.w;
        u1 += xq.x * wb.x + xq.y * wb.y + xq.z * wb.z + xq.w * wb.w;
      }
      float2 uv; uv.x = u0; uv.y = u1;
      *(float2*)(u + (size_t)(b * I_ + i) * OD_ + pr * 2) = uv;
    }
  }
}

// ---------------------------------------------------------------------------
// K2: s0_raw[b,od] = sum_i u[b,i,od]. grid=2048: bx&15=i-chunk(128 i),
// (bx>>4)&15=b, bx>>8=od-block(256). Lane-adjacent od -> coalesced.
// ---------------------------------------------------------------------------
__global__ __launch_bounds__(256) void k_s0sum(
    const float* __restrict__ u, float* __restrict__ s0)
{
  const int t = threadIdx.x;
  const int ic = blockIdx.x & 15;
  const int b = (blockIdx.x >> 4) & 15;
  const int od = (blockIdx.x >> 8) * 256 + t;
  float a = 0.f;
  const float* p = u + (size_t)(b * I_ + ic * 128) * OD_ + od;
  for (int k = 0; k < 128; ++k) a += p[(size_t)k * OD_];
  atomicAdd(&s0[b * OD_ + od], a);
}

// ---------------------------------------------------------------------------
// K3: one routing pass. lane = o; vv recomputed from s-buffers:
//   vv = squash(sA*scaleA + bias) [+ squash(sB + bias)]
// Per i: logit[o] = sum_d u*vv; 64-lane softmax; acc += c*u.
// 4 waves/WG (same b, 4 i-chunks of 8); transposed-LDS cross-wave reduce,
// then 8 atomicAdds/thread. grid = 1024 (16 b x 64 i-groups).
// ---------------------------------------------------------------------------
__global__ __launch_bounds__(256, 3) void k_route(
    const float* __restrict__ u,
    const float* __restrict__ sA, float scaleA,
    const float* __restrict__ sB,  // may be null
    const float* __restrict__ bias,
    float* __restrict__ s_out)
{
  __shared__ float red[4 * 2048];  // 32 KB
  const int t = threadIdx.x;
  const int o = t & 63;
  const int wv = t >> 6;
  const int b = blockIdx.x >> 6;
  const int i0 = ((blockIdx.x & 63) * 4 + wv) * 8;

  float vv[32];
  {
    const int base = b * OD_ + o * 32;
#pragma unroll
    for (int d = 0; d < 32; ++d) {
      float bs = bias[o * 32 + d];
      float val = squashf(sA[base + d] * scaleA + bs);
      if (sB) val += squashf(sB[base + d] + bs);
      vv[d] = val;
    }
  }
  float acc[32];
#pragma unroll
  for (int d = 0; d < 32; ++d) acc[d] = 0.f;

  for (int ii = 0; ii < 8; ++ii) {
    const int i = i0 + ii;
    const float4* up = (const float4*)(u + (size_t)(b * I_ + i) * OD_ + o * 32);
    float uf[32];
#pragma unroll
    for (int qq = 0; qq < 8; ++qq) {
      float4 r = up[qq];
      uf[4 * qq + 0] = r.x; uf[4 * qq + 1] = r.y;
      uf[4 * qq + 2] = r.z; uf[4 * qq + 3] = r.w;
    }
    float logit = 0.f;
#pragma unroll
    for (int d = 0; d < 32; ++d) logit = fmaf(uf[d], vv[d], logit);
    float m = logit;
#pragma unroll
    for (int off = 32; off > 0; off >>= 1) m = fmaxf(m, __shfl_xor(m, off, 64));
    float e = __expf(logit - m);
    float sm = e;
#pragma unroll
    for (int off = 32; off > 0; off >>= 1) sm += __shfl_xor(sm, off, 64);
    float c = e / sm;
#pragma unroll
    for (int d = 0; d < 32; ++d) acc[d] = fmaf(c, uf[d], acc[d]);
  }

  // transposed LDS layout: red[wv][d*64+o] -> conflict-free (contiguous per instr)
#pragma unroll
  for (int d = 0; d < 32; ++d) red[wv * 2048 + d * 64 + o] = acc[d];
  __syncthreads();
#pragma unroll
  for (int k = 0; k < 8; ++k) {
    int od = t * 8 + k;          // od = o*32+d
    int oo = od >> 5, dd = od & 31;
    int a = dd * 64 + oo;
    float r = red[a] + red[2048 + a] + red[4096 + a] + red[6144 + a];
    atomicAdd(&s_out[b * OD_ + od], r);
  }
}

// ---------------------------------------------------------------------------
// K4: out = squash(s2 + bias)
// ---------------------------------------------------------------------------
__global__ void k_out(const float* __restrict__ s2, const float* __restrict__ bias,
                      float* __restrict__ out)
{
  int j = blockIdx.x * 256 + threadIdx.x;
  out[j] = squashf(s2[j] + bias[j & (OD_ - 1)]);
}

extern "C" void kernel_launch(void* const* d_in, const int* in_sizes, int n_in,
                              void* d_out, int out_size, void* d_ws, size_t ws_size,
                              hipStream_t stream) {
  const float* x = (const float*)d_in[0];
  const float* W = (const float*)d_in[1];
  const float* bias = (const float*)d_in[2];
  float* out = (float*)d_out;

  char* ws = (char*)d_ws;
  float* u_ws = (float*)ws;                       // 268,435,456 B (fp32 u_hat)
  float* s0 = (float*)(ws + 268435456ull);        // 3 x 128 KB s-buffers
  float* s1 = s0 + 32768;
  float* s2 = s1 + 32768;

  hipMemsetAsync(s0, 0, 3 * 32768 * sizeof(float), stream);
  k_uhat<<<dim3(1024), dim3(256), 0, stream>>>(x, W, u_ws);
  k_s0sum<<<dim3(2048), dim3(256), 0, stream>>>(u_ws, s0);
  // pass1: v0 = squash(s0/64 + bias)
  k_route<<<dim3(1024), dim3(256), 0, stream>>>(u_ws, s0, 1.0f / 64.0f, nullptr, bias, s1);
  // pass2: vv = v0 + v1 = squash(s0/64+bias) + squash(s1+bias)
  k_route<<<dim3(1024), dim3(256), 0, stream>>>(u_ws, s0, 1.0f / 64.0f, s1, bias, s2);
  k_out<<<dim3(128), dim3(256), 0, stream>>>(s2, bias, out);
}

// Round 7
// 622.653 us; speedup vs baseline: 1.0840x; 1.0840x over previous
//
#include <hip/hip_runtime.h>

// RoutingCapsule: x(16,2048,16) fp32, W(1,2048,64,32,16) fp32, bias(64,32) fp32
// -> v(16,64,32) fp32.   Routing collapses (b_logits additive from 0):
//   s0 = (1/64) sum_i u ; v0 = squash(s0+bias)
//   pass1: c1 = softmax_o(u.v0)      ; s1 = sum_i c1*u
//   pass2: c2 = softmax_o(u.(v0+v1)) ; out = squash(sum_i c2*u + bias)
// u stays fp32 (bf16 u -> 0.465 absmax, R1). NO atomics anywhere: cross-XCD
// device-scope atomicAdd contention is the R2 suspect for 675us vs 205us model.
// R3-R6 failures attributed to infra: R6 control (exact known-good R2 source)
// also died -> source-independent outage. Resubmitting best candidate.
#define B_ 16
#define I_ 2048
#define OD_ 2048
#define EPSQ 1e-9f

__device__ __forceinline__ float squashf(float s) {
  float sq = s * s;
  return sq / (1.0f + sq) * s * rsqrtf(sq + EPSQ);
}

// ---------------------------------------------------------------------------
// K1: u[b,i,od] = sum_p x[b,i,p]*W[i,od,p]  (fp32), plus per-block s0 partials
// (register-accumulated over the block's 8 i, no extra u read).
// grid=1024: bx&3 = od-quarter, bx>>2 = i-chunk ic. Thread owns od-pair pr.
// part0[ic][b][od] : 256*16*2048 fp32 = 32 MB.
// ---------------------------------------------------------------------------
__global__ __launch_bounds__(256) void k_uhat(
    const float* __restrict__ x, const float* __restrict__ W,
    float* __restrict__ u, float* __restrict__ part0)
{
  const int t = threadIdx.x;
  const int q = blockIdx.x & 3;
  const int ic = blockIdx.x >> 2;
  const int i0 = ic * 8;
  const int pr = q * 256 + t;  // od-pair 0..1023

  float s0a[B_], s0b[B_];
#pragma unroll
  for (int b = 0; b < B_; ++b) { s0a[b] = 0.f; s0b[b] = 0.f; }

  for (int ii = 0; ii < 8; ++ii) {
    const int i = i0 + ii;
    const float4* wp = (const float4*)(W + (size_t)(i * OD_ + pr * 2) * 16);
    float4 w[8];
#pragma unroll
    for (int k = 0; k < 8; ++k) w[k] = wp[k];

#pragma unroll
    for (int b = 0; b < B_; ++b) {
      const float4* xp = (const float4*)(x + (size_t)(b * I_ + i) * 16);
      float u0 = 0.f, u1 = 0.f;
#pragma unroll
      for (int qq = 0; qq < 4; ++qq) {
        float4 xq = xp[qq];
        float4 wa = w[qq], wb = w[qq + 4];
        u0 += xq.x * wa.x + xq.y * wa.y + xq.z * wa.z + xq.w * wa.w;
        u1 += xq.x * wb.x + xq.y * wb.y + xq.z * wb.z + xq.w * wb.w;
      }
      float2 uv; uv.x = u0; uv.y = u1;
      *(float2*)(u + (size_t)(b * I_ + i) * OD_ + pr * 2) = uv;
      s0a[b] += u0; s0b[b] += u1;
    }
  }
#pragma unroll
  for (int b = 0; b < B_; ++b) {
    float2 sv; sv.x = s0a[b]; sv.y = s0b[b];
    ((float2*)part0)[(size_t)(ic * B_ + b) * 1024 + pr] = sv;
  }
}

// ---------------------------------------------------------------------------
// K2: s0_raw[b,od] = sum_ic part0[ic][b][od].  grid=128: b=bx>>3, od block.
// ---------------------------------------------------------------------------
__global__ __launch_bounds__(256) void k_s0red(
    const float* __restrict__ part0, float* __restrict__ s0)
{
  const int b = blockIdx.x >> 3;
  const int od = (blockIdx.x & 7) * 256 + threadIdx.x;
  float a = 0.f;
  const float* p = part0 + (size_t)b * OD_ + od;
  for (int ic = 0; ic < 256; ++ic) a += p[(size_t)ic * B_ * OD_];
  s0[b * OD_ + od] = a;
}

// ---------------------------------------------------------------------------
// K3: one routing pass. lane = o; vv = squash(sA*scaleA+bias) [+ squash(sB+bias)].
// Per i: logit = sum_d u*vv; 64-lane softmax over o; acc += c*u.
// 4 waves/WG (same b, 4 i-chunks of 8); transposed-LDS cross-wave reduce;
// block writes its 2048-float partial (NO atomics). grid=1024 (b*64+grp).
// ---------------------------------------------------------------------------
__global__ __launch_bounds__(256, 3) void k_route(
    const float* __restrict__ u,
    const float* __restrict__ sA, float scaleA,
    const float* __restrict__ sB,  // may be null
    const float* __restrict__ bias,
    float* __restrict__ part)
{
  __shared__ float red[4 * 2048];  // 32 KB
  const int t = threadIdx.x;
  const int o = t & 63;
  const int wv = t >> 6;
  const int b = blockIdx.x >> 6;
  const int i0 = ((blockIdx.x & 63) * 4 + wv) * 8;

  float vv[32];
  {
    const int base = b * OD_ + o * 32;
#pragma unroll
    for (int d = 0; d < 32; ++d) {
      float bs = bias[o * 32 + d];
      float val = squashf(sA[base + d] * scaleA + bs);
      if (sB) val += squashf(sB[base + d] + bs);
      vv[d] = val;
    }
  }
  float acc[32];
#pragma unroll
  for (int d = 0; d < 32; ++d) acc[d] = 0.f;

  for (int ii = 0; ii < 8; ++ii) {
    const int i = i0 + ii;
    const float4* up = (const float4*)(u + (size_t)(b * I_ + i) * OD_ + o * 32);
    float uf[32];
#pragma unroll
    for (int qq = 0; qq < 8; ++qq) {
      float4 r = up[qq];
      uf[4 * qq + 0] = r.x; uf[4 * qq + 1] = r.y;
      uf[4 * qq + 2] = r.z; uf[4 * qq + 3] = r.w;
    }
    float logit = 0.f;
#pragma unroll
    for (int d = 0; d < 32; ++d) logit = fmaf(uf[d], vv[d], logit);
    float m = logit;
#pragma unroll
    for (int off = 32; off > 0; off >>= 1) m = fmaxf(m, __shfl_xor(m, off, 64));
    float e = __expf(logit - m);
    float sm = e;
#pragma unroll
    for (int off = 32; off > 0; off >>= 1) sm += __shfl_xor(sm, off, 64);
    float c = e / sm;
#pragma unroll
    for (int d = 0; d < 32; ++d) acc[d] = fmaf(c, uf[d], acc[d]);
  }

  // transposed LDS layout red[wv][d*64+o]: conflict-free contiguous writes
#pragma unroll
  for (int d = 0; d < 32; ++d) red[wv * 2048 + d * 64 + o] = acc[d];
  __syncthreads();
#pragma unroll
  for (int k = 0; k < 8; ++k) {
    int od = t * 8 + k;  // od = o*32+d
    int oo = od >> 5, dd = od & 31;
    int a = dd * 64 + oo;
    part[(size_t)blockIdx.x * OD_ + od] =
        red[a] + red[2048 + a] + red[4096 + a] + red[6144 + a];
  }
}

// ---------------------------------------------------------------------------
// K4: s1[b,od] = sum_g part[(b*64+g)][od].  grid=128.
// ---------------------------------------------------------------------------
__global__ __launch_bounds__(256) void k_s1red(
    const float* __restrict__ part, float* __restrict__ s1)
{
  const int b = blockIdx.x >> 3;
  const int od = (blockIdx.x & 7) * 256 + threadIdx.x;
  float a = 0.f;
  const float* p = part + (size_t)b * 64 * OD_ + od;
#pragma unroll 4
  for (int g = 0; g < 64; ++g) a += p[(size_t)g * OD_];
  s1[b * OD_ + od] = a;
}

// ---------------------------------------------------------------------------
// K5: out[b,od] = squash(sum_g part2 + bias).  grid=128.
// ---------------------------------------------------------------------------
__global__ __launch_bounds__(256) void k_outred(
    const float* __restrict__ part, const float* __restrict__ bias,
    float* __restrict__ out)
{
  const int b = blockIdx.x >> 3;
  const int od = (blockIdx.x & 7) * 256 + threadIdx.x;
  float a = 0.f;
  const float* p = part + (size_t)b * 64 * OD_ + od;
#pragma unroll 4
  for (int g = 0; g < 64; ++g) a += p[(size_t)g * OD_];
  out[b * OD_ + od] = squashf(a + bias[od]);
}

extern "C" void kernel_launch(void* const* d_in, const int* in_sizes, int n_in,
                              void* d_out, int out_size, void* d_ws, size_t ws_size,
                              hipStream_t stream) {
  const float* x = (const float*)d_in[0];
  const float* W = (const float*)d_in[1];
  const float* bias = (const float*)d_in[2];
  float* out = (float*)d_out;

  char* ws = (char*)d_ws;
  float* u_ws  = (float*)ws;                          // 256 MB fp32 u_hat
  float* part0 = (float*)(ws + 268435456ull);         // 32 MB s0 partials
  float* part1 = (float*)(ws + 302055424ull);         // 8 MB route partials
  float* part2 = (float*)(ws + 310444032ull);         // 8 MB route partials
  float* s0    = (float*)(ws + 318832640ull);         // 128 KB
  float* s1    = s0 + 32768;                          // 128 KB

  k_uhat <<<dim3(1024), dim3(256), 0, stream>>>(x, W, u_ws, part0);
  k_s0red<<<dim3(128),  dim3(256), 0, stream>>>(part0, s0);
  // pass1: v0 = squash(s0/64 + bias)
  k_route<<<dim3(1024), dim3(256), 0, stream>>>(u_ws, s0, 1.0f / 64.0f, nullptr, bias, part1);
  k_s1red<<<dim3(128),  dim3(256), 0, stream>>>(part1, s1);
  // pass2: vv = squash(s0/64+bias) + squash(s1+bias)
  k_route<<<dim3(1024), dim3(256), 0, stream>>>(u_ws, s0, 1.0f / 64.0f, s1, bias, part2);
  k_outred<<<dim3(128), dim3(256), 0, stream>>>(part2, bias, out);
}